// Round 3
// baseline (198.961 us; speedup 1.0000x reference)
//
#include <hip/hip_runtime.h>
#include <math.h>

// LiftSplatShoot constants
#define DNUM 41
#define FH 8
#define FW 22
#define CAMC 64
#define NB 8
#define NCAM 6
#define BN 48
#define NXX 200
#define NXY 200
#define KVOX 40000                // NXX*NXY (NXZ=1)
#define CAM_CH (DNUM + CAMC)      // 105
#define HW (FH * FW)              // 176
#define CAM_STRIDE (CAM_CH * HW)  // 18480
#define OUT_PER_B (CAMC * KVOX)   // 2,560,000
#define PIXT (BN * HW)            // 8448 pixels total
#define NPTS (PIXT * DNUM)        // 346,368 points
#define KTOT (NB * KVOX)          // 320,000 voxels total
#define NBLKA (KTOT / 256)        // 1250 scan blocks

// Replicates reference safe_inverse_3x3 in float32, same op order, no fma.
__device__ __forceinline__ void inv3x3(const float* __restrict__ m, float* __restrict__ o) {
  #pragma clang fp contract(off)
  float a=m[0], b=m[1], c=m[2];
  float d=m[3], e=m[4], f=m[5];
  float g=m[6], h=m[7], i=m[8];
  float A  =  e*i - f*h;
  float Bc = -(d*i - f*g);
  float Cc =  d*h - e*g;
  float Dc = -(b*i - c*h);
  float E  =  a*i - c*g;
  float F  = -(a*h - b*g);
  float G  =  b*f - c*e;
  float H  = -(a*f - c*d);
  float I  =  a*e - b*d;
  float det = fmaxf((a*A + b*Bc) + c*Cc, 1e-8f);
  o[0]=A/det;  o[1]=Dc/det; o[2]=G/det;
  o[3]=Bc/det; o[4]=E/det;  o[5]=H/det;
  o[6]=Cc/det; o[7]=F/det;  o[8]=I/det;
}

// Per-(b,n): P = inv(post_rots), M = rots @ inv(intrins). 18 floats each -> prep.
__global__ void lss_prep(const float* __restrict__ rots,
                         const float* __restrict__ intrins,
                         const float* __restrict__ post_rots,
                         float* __restrict__ prep) {
  #pragma clang fp contract(off)
  int bn = threadIdx.x;
  if (bn >= BN) return;
  float P[9], IC[9];
  inv3x3(post_rots + bn*9, P);
  inv3x3(intrins + bn*9, IC);
  const float* R = rots + bn*9;
  float* o = prep + bn*18;
  #pragma unroll
  for (int j = 0; j < 9; j++) o[j] = P[j];
  #pragma unroll
  for (int r = 0; r < 3; r++)
    #pragma unroll
    for (int k = 0; k < 3; k++)
      o[9 + r*3 + k] = (R[r*3+0]*IC[0+k] + R[r*3+1]*IC[3+k]) + R[r*3+2]*IC[6+k];
}

// One wave per pixel: softmax, geometry, per-point records + voxel counts,
// and channel-major feature transpose featT[c*PIXT + pixel].
__global__ __launch_bounds__(64) void lss_pixel(const float* __restrict__ cam_out,
                                                const float* __restrict__ trans,
                                                const float* __restrict__ post_trans,
                                                const float* __restrict__ prep,
                                                float* __restrict__ featT,
                                                int* __restrict__ recVox,
                                                float* __restrict__ recW,
                                                int* __restrict__ counts) {
  #pragma clang fp contract(off)
  const int blk = blockIdx.x;         // pixel id: bn*HW + pix
  const int bn  = blk / HW;
  const int pix = blk % HW;
  const int h   = pix / FW;
  const int w   = pix % FW;
  const int b   = bn / NCAM;
  const int tid = threadIdx.x;

  __shared__ float sP[9], sM[9], sPT[3], sTR[3];
  if (tid < 9)       sP[tid]      = prep[bn*18 + tid];
  else if (tid < 18) sM[tid-9]    = prep[bn*18 + tid];
  else if (tid < 21) sPT[tid-18]  = post_trans[bn*3 + (tid-18)];
  else if (tid < 24) sTR[tid-21]  = trans[bn*3 + (tid-21)];
  __syncthreads();

  const int base = bn*CAM_STRIDE + h*FW + w;

  // ---- softmax over 41 depth logits (lanes 0..40 active, wave64 shuffles) ----
  float logit = (tid < DNUM) ? cam_out[base + tid*HW] : -INFINITY;
  float mx = logit;
  #pragma unroll
  for (int off = 32; off >= 1; off >>= 1) mx = fmaxf(mx, __shfl_xor(mx, off, 64));
  float e = expf(logit - mx);
  float s = e;
  #pragma unroll
  for (int off = 32; off >= 1; off >>= 1) s += __shfl_xor(s, off, 64);
  float depth = e / s;

  // ---- geometry + voxel index + record for lane's depth bin ----
  if (tid < DNUM) {
    float fx = (float)((double)w * (351.0 / 21.0));
    float fy = (float)((double)h * (127.0 / 7.0));
    float fz = 4.0f + (float)tid;
    float p0 = fx - sPT[0], p1 = fy - sPT[1], p2 = fz - sPT[2];
    float q0 = (sP[0]*p0 + sP[1]*p1) + sP[2]*p2;
    float q1 = (sP[3]*p0 + sP[4]*p1) + sP[5]*p2;
    float q2 = (sP[6]*p0 + sP[7]*p1) + sP[8]*p2;
    float r0 = q0*q2, r1 = q1*q2, r2 = q2;
    float g0 = ((sM[0]*r0 + sM[1]*r1) + sM[2]*r2) + sTR[0];
    float g1 = ((sM[3]*r0 + sM[4]*r1) + sM[5]*r2) + sTR[1];
    float g2 = ((sM[6]*r0 + sM[7]*r1) + sM[8]*r2) + sTR[2];
    int ix = (int)((g0 + 50.0f) / 0.5f);
    int iy = (int)((g1 + 50.0f) / 0.5f);
    int iz = (int)((g2 + 10.0f) / 20.0f);
    bool kept = (ix >= 0) & (ix < NXX) & (iy >= 0) & (iy < NXY) & (iz == 0);
    int gv = kept ? (b*KVOX + ix*NXY + iy) : -1;
    recVox[blk*DNUM + tid] = gv;
    recW[blk*DNUM + tid]   = depth;
    if (kept) atomicAdd(&counts[gv], 1);
  }

  // ---- feature transpose: lane = channel ----
  featT[(size_t)tid*PIXT + blk] = cam_out[base + (DNUM + tid)*HW];
}

// Scan step A: per-256-block sums of counts.
__global__ __launch_bounds__(256) void lss_scanA(const int* __restrict__ counts,
                                                 int* __restrict__ bsums) {
  __shared__ int red[256];
  int tx = threadIdx.x;
  red[tx] = counts[blockIdx.x*256 + tx];
  __syncthreads();
  #pragma unroll
  for (int off = 128; off >= 1; off >>= 1) {
    if (tx < off) red[tx] += red[tx + off];
    __syncthreads();
  }
  if (tx == 0) bsums[blockIdx.x] = red[0];
}

// Scan step B: exclusive scan of the 1250 block sums (single block).
__global__ __launch_bounds__(256) void lss_scanB(int* __restrict__ bsums) {
  __shared__ int tmp[256];
  int tx = threadIdx.x;
  int running = 0;
  for (int c0 = 0; c0 < NBLKA; c0 += 256) {
    int i = c0 + tx;
    int v = (i < NBLKA) ? bsums[i] : 0;
    tmp[tx] = v;
    __syncthreads();
    #pragma unroll
    for (int off = 1; off < 256; off <<= 1) {
      int t = (tx >= off) ? tmp[tx - off] : 0;
      __syncthreads();
      tmp[tx] += t;
      __syncthreads();
    }
    int incl  = tmp[tx];
    int total = tmp[255];
    if (i < NBLKA) bsums[i] = running + incl - v;  // exclusive
    running += total;
    __syncthreads();
  }
}

// Scan step C: per-block exclusive scan + scanned base -> offsets & cursors.
__global__ __launch_bounds__(256) void lss_scanC(const int* __restrict__ counts,
                                                 const int* __restrict__ bsums,
                                                 int* __restrict__ offsets,
                                                 int* __restrict__ cursors) {
  __shared__ int tmp[256];
  int tx = threadIdx.x;
  int i  = blockIdx.x*256 + tx;
  int v  = counts[i];
  tmp[tx] = v;
  __syncthreads();
  #pragma unroll
  for (int off = 1; off < 256; off <<= 1) {
    int t = (tx >= off) ? tmp[tx - off] : 0;
    __syncthreads();
    tmp[tx] += t;
    __syncthreads();
  }
  int excl = bsums[blockIdx.x] + tmp[tx] - v;
  offsets[i] = excl;
  cursors[i] = excl;
}

// Place kept points into per-voxel lists (pixel id + weight packed 8B).
__global__ __launch_bounds__(256) void lss_place(const int* __restrict__ recVox,
                                                 const float* __restrict__ recW,
                                                 int* __restrict__ cursors,
                                                 int2* __restrict__ listPW) {
  int pt = blockIdx.x*256 + threadIdx.x;   // NPTS = 1353*256 exactly
  int gv = recVox[pt];
  if (gv < 0) return;
  int slot = atomicAdd(&cursors[gv], 1);
  int pix  = pt / DNUM;
  listPW[slot] = make_int2(pix, __float_as_int(recW[pt]));
}

// Gather: one thread per output element, coalesced write, no atomics.
__global__ __launch_bounds__(320) void lss_gather(const int* __restrict__ offsets,
                                                  const int* __restrict__ counts,
                                                  const int2* __restrict__ listPW,
                                                  const float* __restrict__ featT,
                                                  float* __restrict__ out) {
  const int xy = blockIdx.x*320 + threadIdx.x;   // 125*320 = 40000 exactly
  const int c  = blockIdx.y;
  const int b  = blockIdx.z;
  const int v  = b*KVOX + xy;
  int s = offsets[v];
  int n = counts[v];
  const float* __restrict__ fc = featT + (size_t)c*PIXT;
  float acc = 0.0f;
  for (int k = 0; k < n; k++) {
    int2 e = listPW[s + k];
    acc += __int_as_float(e.y) * fc[e.x];
  }
  out[(size_t)b*OUT_PER_B + (size_t)c*KVOX + xy] = acc;
}

// Fallback (tiny ws): direct atomic scatter into out (round-1 structure).
__global__ __launch_bounds__(64) void lss_scatter_direct(const float* __restrict__ cam_out,
                                                         const float* __restrict__ trans,
                                                         const float* __restrict__ post_trans,
                                                         const float* __restrict__ prep,
                                                         float* __restrict__ out) {
  #pragma clang fp contract(off)
  const int blk = blockIdx.x;
  const int bn  = blk / HW;
  const int pix = blk % HW;
  const int h   = pix / FW;
  const int w   = pix % FW;
  const int b   = bn / NCAM;
  const int tid = threadIdx.x;
  __shared__ float sP[9], sM[9], sPT[3], sTR[3];
  __shared__ float sDepth[DNUM];
  __shared__ int   sVoff[DNUM];
  if (tid < 9)       sP[tid]      = prep[bn*18 + tid];
  else if (tid < 18) sM[tid-9]    = prep[bn*18 + tid];
  else if (tid < 21) sPT[tid-18]  = post_trans[bn*3 + (tid-18)];
  else if (tid < 24) sTR[tid-21]  = trans[bn*3 + (tid-21)];
  __syncthreads();
  const int base = bn*CAM_STRIDE + h*FW + w;
  float logit = (tid < DNUM) ? cam_out[base + tid*HW] : -INFINITY;
  float mx = logit;
  #pragma unroll
  for (int off = 32; off >= 1; off >>= 1) mx = fmaxf(mx, __shfl_xor(mx, off, 64));
  float e = expf(logit - mx);
  float s = e;
  #pragma unroll
  for (int off = 32; off >= 1; off >>= 1) s += __shfl_xor(s, off, 64);
  float depth = e / s;
  if (tid < DNUM) {
    float fx = (float)((double)w * (351.0 / 21.0));
    float fy = (float)((double)h * (127.0 / 7.0));
    float fz = 4.0f + (float)tid;
    float p0 = fx - sPT[0], p1 = fy - sPT[1], p2 = fz - sPT[2];
    float q0 = (sP[0]*p0 + sP[1]*p1) + sP[2]*p2;
    float q1 = (sP[3]*p0 + sP[4]*p1) + sP[5]*p2;
    float q2 = (sP[6]*p0 + sP[7]*p1) + sP[8]*p2;
    float r0 = q0*q2, r1 = q1*q2, r2 = q2;
    float g0 = ((sM[0]*r0 + sM[1]*r1) + sM[2]*r2) + sTR[0];
    float g1 = ((sM[3]*r0 + sM[4]*r1) + sM[5]*r2) + sTR[1];
    float g2 = ((sM[6]*r0 + sM[7]*r1) + sM[8]*r2) + sTR[2];
    int ix = (int)((g0 + 50.0f) / 0.5f);
    int iy = (int)((g1 + 50.0f) / 0.5f);
    int iz = (int)((g2 + 10.0f) / 20.0f);
    bool kept = (ix >= 0) & (ix < NXX) & (iy >= 0) & (iy < NXY) & (iz == 0);
    sVoff[tid]  = kept ? (ix*NXY + iy) : -1;
    sDepth[tid] = depth;
  }
  __syncthreads();
  const float feat = cam_out[base + (DNUM + tid)*HW];
  float* outb = out + (size_t)b*OUT_PER_B + (size_t)tid*KVOX;
  #pragma unroll 1
  for (int d = 0; d < DNUM; d++) {
    int v = sVoff[d];
    if (v >= 0) atomicAdd(outb + v, sDepth[d] * feat);
  }
}

extern "C" void kernel_launch(void* const* d_in, const int* in_sizes, int n_in,
                              void* d_out, int out_size, void* d_ws, size_t ws_size,
                              hipStream_t stream) {
  const float* cam_out    = (const float*)d_in[0];
  const float* rots       = (const float*)d_in[1];
  const float* trans      = (const float*)d_in[2];
  const float* intrins    = (const float*)d_in[3];
  const float* post_rots  = (const float*)d_in[4];
  const float* post_trans = (const float*)d_in[5];
  float* out = (float*)d_out;
  float* ws  = (float*)d_ws;

  // ws layout (4-byte units); listPW first for 8B alignment.
  int2*  listPW  = (int2*)ws;                         // NPTS int2
  float* prep    = ws + 2*(size_t)NPTS;               // 864
  float* featT   = prep + BN*18;                      // PIXT*CAMC
  int*   recVox  = (int*)(featT + (size_t)PIXT*CAMC); // NPTS
  float* recW    = (float*)(recVox + NPTS);           // NPTS
  int*   counts  = (int*)(recW + NPTS);               // KTOT
  int*   offsets = counts + KTOT;                     // KTOT
  int*   cursors = offsets + KTOT;                    // KTOT
  int*   bsums   = cursors + KTOT;                    // NBLKA
  const size_t need = ((size_t)(bsums + NBLKA) - (size_t)ws);

  if (ws_size >= need) {
    hipMemsetAsync(counts, 0, (size_t)KTOT*sizeof(int), stream);
    lss_prep<<<1, 64, 0, stream>>>(rots, intrins, post_rots, prep);
    lss_pixel<<<PIXT, 64, 0, stream>>>(cam_out, trans, post_trans, prep,
                                       featT, recVox, recW, counts);
    lss_scanA<<<NBLKA, 256, 0, stream>>>(counts, bsums);
    lss_scanB<<<1, 256, 0, stream>>>(bsums);
    lss_scanC<<<NBLKA, 256, 0, stream>>>(counts, bsums, offsets, cursors);
    lss_place<<<NPTS/256, 256, 0, stream>>>(recVox, recW, cursors, listPW);
    dim3 g(KVOX/320, CAMC, NB);
    lss_gather<<<g, 320, 0, stream>>>(offsets, counts, listPW, featT, out);
  } else {
    hipMemsetAsync(out, 0, (size_t)out_size*sizeof(float), stream);
    lss_prep<<<1, 64, 0, stream>>>(rots, intrins, post_rots, ws);
    lss_scatter_direct<<<PIXT, 64, 0, stream>>>(cam_out, trans, post_trans, ws, out);
  }
}

// Round 4
// 130.279 us; speedup vs baseline: 1.5272x; 1.5272x over previous
//
#include <hip/hip_runtime.h>
#include <math.h>

// LiftSplatShoot constants
#define DNUM 41
#define FH 8
#define FW 22
#define CAMC 64
#define NB 8
#define NCAM 6
#define BN 48
#define NXX 200
#define NXY 200
#define KVOX 40000                // NXX*NXY (NXZ=1)
#define CAM_CH (DNUM + CAMC)      // 105
#define HW (FH * FW)              // 176
#define CAM_STRIDE (CAM_CH * HW)  // 18480
#define OUT_PER_B (CAMC * KVOX)   // 2,560,000
#define SCRATCH_FLOATS ((size_t)NB * KVOX * CAMC)   // 20,480,000 floats = 81.92 MB

// Replicates reference safe_inverse_3x3 in float32, same op order, no fma.
__device__ __forceinline__ void inv3x3(const float* __restrict__ m, float* __restrict__ o) {
  #pragma clang fp contract(off)
  float a=m[0], b=m[1], c=m[2];
  float d=m[3], e=m[4], f=m[5];
  float g=m[6], h=m[7], i=m[8];
  float A  =  e*i - f*h;
  float Bc = -(d*i - f*g);
  float Cc =  d*h - e*g;
  float Dc = -(b*i - c*h);
  float E  =  a*i - c*g;
  float F  = -(a*h - b*g);
  float G  =  b*f - c*e;
  float H  = -(a*f - c*d);
  float I  =  a*e - b*d;
  float det = fmaxf((a*A + b*Bc) + c*Cc, 1e-8f);
  o[0]=A/det;  o[1]=Dc/det; o[2]=G/det;
  o[3]=Bc/det; o[4]=E/det;  o[5]=H/det;
  o[6]=Cc/det; o[7]=F/det;  o[8]=I/det;
}

// Per-(b,n): P = inv(post_rots), M = rots @ inv(intrins). 18 floats each -> prep.
__global__ void lss_prep(const float* __restrict__ rots,
                         const float* __restrict__ intrins,
                         const float* __restrict__ post_rots,
                         float* __restrict__ prep) {
  #pragma clang fp contract(off)
  int bn = threadIdx.x;
  if (bn >= BN) return;
  float P[9], IC[9];
  inv3x3(post_rots + bn*9, P);
  inv3x3(intrins + bn*9, IC);
  const float* R = rots + bn*9;
  float* o = prep + bn*18;
  #pragma unroll
  for (int j = 0; j < 9; j++) o[j] = P[j];
  #pragma unroll
  for (int r = 0; r < 3; r++)
    #pragma unroll
    for (int k = 0; k < 3; k++)
      o[9 + r*3 + k] = (R[r*3+0]*IC[0+k] + R[r*3+1]*IC[3+k]) + R[r*3+2]*IC[6+k];
}

// One wave per (bn, w) column: 8 rows x 41 depths. Rows that hit the SAME
// voxel at a given depth are merged in registers before the atomic (z_ego is
// one collapsed bin, so rows mostly coincide) -> ~8x fewer atomics.
__global__ __launch_bounds__(64) void lss_scatter_col(const float* __restrict__ cam_out,
                                                      const float* __restrict__ trans,
                                                      const float* __restrict__ post_trans,
                                                      const float* __restrict__ prep,
                                                      float* __restrict__ dst) {
  #pragma clang fp contract(off)
  const int blk = blockIdx.x;         // 0 .. BN*FW-1
  const int bn  = blk / FW;
  const int w   = blk % FW;
  const int b   = bn / NCAM;
  const int tid = threadIdx.x;

  __shared__ float sP[9], sM[9], sPT[3], sTR[3];
  __shared__ float sDep[FH][DNUM + 1];
  __shared__ int   sVox[FH][DNUM + 1];
  __shared__ float sFeat[FH][CAMC];

  if (tid < 9)       sP[tid]      = prep[bn*18 + tid];
  else if (tid < 18) sM[tid-9]    = prep[bn*18 + tid];
  else if (tid < 21) sPT[tid-18]  = post_trans[bn*3 + (tid-18)];
  else if (tid < 24) sTR[tid-21]  = trans[bn*3 + (tid-21)];
  __syncthreads();

  const int colbase = bn*CAM_STRIDE + w;   // + c*HW + h*FW

  // ---- features: lane = channel, all 8 rows ----
  #pragma unroll
  for (int h = 0; h < FH; h++)
    sFeat[h][tid] = cam_out[colbase + (DNUM + tid)*HW + h*FW];

  const float fx = (float)((double)w * (351.0 / 21.0));

  // ---- per-row softmax (wave64 shuffles) + geometry (lane = depth) ----
  for (int h = 0; h < FH; h++) {
    float logit = (tid < DNUM) ? cam_out[colbase + tid*HW + h*FW] : -INFINITY;
    float mx = logit;
    #pragma unroll
    for (int off = 32; off >= 1; off >>= 1) mx = fmaxf(mx, __shfl_xor(mx, off, 64));
    float e = expf(logit - mx);
    float s = e;
    #pragma unroll
    for (int off = 32; off >= 1; off >>= 1) s += __shfl_xor(s, off, 64);
    if (tid < DNUM) {
      float fy = (float)((double)h * (127.0 / 7.0));
      float fz = 4.0f + (float)tid;
      float p0 = fx - sPT[0], p1 = fy - sPT[1], p2 = fz - sPT[2];
      float q0 = (sP[0]*p0 + sP[1]*p1) + sP[2]*p2;
      float q1 = (sP[3]*p0 + sP[4]*p1) + sP[5]*p2;
      float q2 = (sP[6]*p0 + sP[7]*p1) + sP[8]*p2;
      float r0 = q0*q2, r1 = q1*q2, r2 = q2;
      float g0 = ((sM[0]*r0 + sM[1]*r1) + sM[2]*r2) + sTR[0];
      float g1 = ((sM[3]*r0 + sM[4]*r1) + sM[5]*r2) + sTR[1];
      float g2 = ((sM[6]*r0 + sM[7]*r1) + sM[8]*r2) + sTR[2];
      int ix = (int)((g0 + 50.0f) / 0.5f);
      int iy = (int)((g1 + 50.0f) / 0.5f);
      int iz = (int)((g2 + 10.0f) / 20.0f);
      bool kept = (ix >= 0) & (ix < NXX) & (iy >= 0) & (iy < NXY) & (iz == 0);
      sVox[h][tid] = kept ? (ix*NXY + iy) : -1;
      sDep[h][tid] = e / s;
    }
  }
  __syncthreads();

  // ---- merged scatter: lane = channel; dedup rows with equal voxel ----
  float* __restrict__ sb = dst + (size_t)b*KVOX*CAMC + tid;
  for (int d = 0; d < DNUM; d++) {
    unsigned done = 0;
    #pragma unroll
    for (int h = 0; h < FH; h++) {
      if ((done >> h) & 1u) continue;
      int v = sVox[h][d];            // wave-uniform
      if (v < 0) continue;
      float wsum = sDep[h][d] * sFeat[h][tid];
      #pragma unroll
      for (int h2 = h + 1; h2 < FH; h2++) {
        if (sVox[h2][d] == v) {
          wsum += sDep[h2][d] * sFeat[h2][tid];
          done |= 1u << h2;
        }
      }
      atomicAdd(sb + (size_t)v*CAMC, wsum);   // 64 lanes -> 4 cache lines
    }
  }
}

// (B, XY, C) -> (B, C, XY) tiled transpose; writes EVERY output element.
__global__ __launch_bounds__(256) void lss_transpose(const float* __restrict__ src,
                                                     float* __restrict__ out) {
  __shared__ float tile[64][65];
  const int b  = blockIdx.y;
  const int v0 = blockIdx.x * 64;                 // 625 * 64 = 40000 exactly
  const int tx = threadIdx.x & 63;
  const int ty = threadIdx.x >> 6;                // 0..3
  const float* s = src + ((size_t)b*KVOX + v0) * CAMC;
  #pragma unroll
  for (int r = ty; r < 64; r += 4)
    tile[r][tx] = s[r*CAMC + tx];                 // coalesced
  __syncthreads();
  float* dstp = out + (size_t)b*OUT_PER_B + v0;
  #pragma unroll
  for (int r = ty; r < 64; r += 4)
    dstp[(size_t)r*KVOX + tx] = tile[tx][r];      // coalesced, bank-conflict-free
}

// Fallback (tiny ws): direct atomic scatter into out (round-1 structure).
__global__ __launch_bounds__(64) void lss_scatter_direct(const float* __restrict__ cam_out,
                                                         const float* __restrict__ trans,
                                                         const float* __restrict__ post_trans,
                                                         const float* __restrict__ prep,
                                                         float* __restrict__ out) {
  #pragma clang fp contract(off)
  const int blk = blockIdx.x;
  const int bn  = blk / HW;
  const int pix = blk % HW;
  const int h   = pix / FW;
  const int w   = pix % FW;
  const int b   = bn / NCAM;
  const int tid = threadIdx.x;
  __shared__ float sP[9], sM[9], sPT[3], sTR[3];
  __shared__ float sDepth[DNUM];
  __shared__ int   sVoff[DNUM];
  if (tid < 9)       sP[tid]      = prep[bn*18 + tid];
  else if (tid < 18) sM[tid-9]    = prep[bn*18 + tid];
  else if (tid < 21) sPT[tid-18]  = post_trans[bn*3 + (tid-18)];
  else if (tid < 24) sTR[tid-21]  = trans[bn*3 + (tid-21)];
  __syncthreads();
  const int base = bn*CAM_STRIDE + h*FW + w;
  float logit = (tid < DNUM) ? cam_out[base + tid*HW] : -INFINITY;
  float mx = logit;
  #pragma unroll
  for (int off = 32; off >= 1; off >>= 1) mx = fmaxf(mx, __shfl_xor(mx, off, 64));
  float e = expf(logit - mx);
  float s = e;
  #pragma unroll
  for (int off = 32; off >= 1; off >>= 1) s += __shfl_xor(s, off, 64);
  float depth = e / s;
  if (tid < DNUM) {
    float fx = (float)((double)w * (351.0 / 21.0));
    float fy = (float)((double)h * (127.0 / 7.0));
    float fz = 4.0f + (float)tid;
    float p0 = fx - sPT[0], p1 = fy - sPT[1], p2 = fz - sPT[2];
    float q0 = (sP[0]*p0 + sP[1]*p1) + sP[2]*p2;
    float q1 = (sP[3]*p0 + sP[4]*p1) + sP[5]*p2;
    float q2 = (sP[6]*p0 + sP[7]*p1) + sP[8]*p2;
    float r0 = q0*q2, r1 = q1*q2, r2 = q2;
    float g0 = ((sM[0]*r0 + sM[1]*r1) + sM[2]*r2) + sTR[0];
    float g1 = ((sM[3]*r0 + sM[4]*r1) + sM[5]*r2) + sTR[1];
    float g2 = ((sM[6]*r0 + sM[7]*r1) + sM[8]*r2) + sTR[2];
    int ix = (int)((g0 + 50.0f) / 0.5f);
    int iy = (int)((g1 + 50.0f) / 0.5f);
    int iz = (int)((g2 + 10.0f) / 20.0f);
    bool kept = (ix >= 0) & (ix < NXX) & (iy >= 0) & (iy < NXY) & (iz == 0);
    sVoff[tid]  = kept ? (ix*NXY + iy) : -1;
    sDepth[tid] = depth;
  }
  __syncthreads();
  const float feat = cam_out[base + (DNUM + tid)*HW];
  float* outb = out + (size_t)b*OUT_PER_B + (size_t)tid*KVOX;
  #pragma unroll 1
  for (int d = 0; d < DNUM; d++) {
    int v = sVoff[d];
    if (v >= 0) atomicAdd(outb + v, sDepth[d] * feat);
  }
}

extern "C" void kernel_launch(void* const* d_in, const int* in_sizes, int n_in,
                              void* d_out, int out_size, void* d_ws, size_t ws_size,
                              hipStream_t stream) {
  const float* cam_out    = (const float*)d_in[0];
  const float* rots       = (const float*)d_in[1];
  const float* trans      = (const float*)d_in[2];
  const float* intrins    = (const float*)d_in[3];
  const float* post_rots  = (const float*)d_in[4];
  const float* post_trans = (const float*)d_in[5];
  float* out = (float*)d_out;
  float* ws  = (float*)d_ws;

  const size_t scratch_bytes = SCRATCH_FLOATS * sizeof(float);
  const bool use_scratch = ws_size >= scratch_bytes + (size_t)BN*18*sizeof(float);
  float* prep = use_scratch ? (ws + SCRATCH_FLOATS) : ws;

  lss_prep<<<1, 64, 0, stream>>>(rots, intrins, post_rots, prep);

  if (use_scratch) {
    hipMemsetAsync(ws, 0, scratch_bytes, stream);
    lss_scatter_col<<<BN * FW, 64, 0, stream>>>(cam_out, trans, post_trans, prep, ws);
    dim3 g(KVOX / 64, NB);
    lss_transpose<<<g, 256, 0, stream>>>(ws, out);
  } else {
    hipMemsetAsync(out, 0, (size_t)out_size * sizeof(float), stream);
    lss_scatter_direct<<<BN * HW, 64, 0, stream>>>(cam_out, trans, post_trans, prep, out);
  }
}

// Round 5
// 102.354 us; speedup vs baseline: 1.9439x; 1.2728x over previous
//
#include <hip/hip_runtime.h>
#include <math.h>

// LiftSplatShoot constants
#define DNUM 41
#define FH 8
#define FW 22
#define CAMC 64
#define NB 8
#define NCAM 6
#define BN 48
#define NXX 200
#define NXY 200
#define KVOX 40000                // NXX*NXY (NXZ=1)
#define CAM_CH (DNUM + CAMC)      // 105
#define HW (FH * FW)              // 176
#define CAM_STRIDE (CAM_CH * HW)  // 18480
#define OUT_PER_B (CAMC * KVOX)   // 2,560,000
#define SCRATCH_FLOATS ((size_t)NB * KVOX * CAMC)   // 20,480,000 floats = 81.92 MB

// Replicates reference safe_inverse_3x3 in float32, same op order, no fma.
__device__ __forceinline__ void inv3x3(const float* __restrict__ m, float* __restrict__ o) {
  #pragma clang fp contract(off)
  float a=m[0], b=m[1], c=m[2];
  float d=m[3], e=m[4], f=m[5];
  float g=m[6], h=m[7], i=m[8];
  float A  =  e*i - f*h;
  float Bc = -(d*i - f*g);
  float Cc =  d*h - e*g;
  float Dc = -(b*i - c*h);
  float E  =  a*i - c*g;
  float F  = -(a*h - b*g);
  float G  =  b*f - c*e;
  float H  = -(a*f - c*d);
  float I  =  a*e - b*d;
  float det = fmaxf((a*A + b*Bc) + c*Cc, 1e-8f);
  o[0]=A/det;  o[1]=Dc/det; o[2]=G/det;
  o[3]=Bc/det; o[4]=E/det;  o[5]=H/det;
  o[6]=Cc/det; o[7]=F/det;  o[8]=I/det;
}

// Per-(b,n): P = inv(post_rots), M = rots @ inv(intrins). 18 floats each -> prep.
__global__ void lss_prep(const float* __restrict__ rots,
                         const float* __restrict__ intrins,
                         const float* __restrict__ post_rots,
                         float* __restrict__ prep) {
  #pragma clang fp contract(off)
  int bn = threadIdx.x;
  if (bn >= BN) return;
  float P[9], IC[9];
  inv3x3(post_rots + bn*9, P);
  inv3x3(intrins + bn*9, IC);
  const float* R = rots + bn*9;
  float* o = prep + bn*18;
  #pragma unroll
  for (int j = 0; j < 9; j++) o[j] = P[j];
  #pragma unroll
  for (int r = 0; r < 3; r++)
    #pragma unroll
    for (int k = 0; k < 3; k++)
      o[9 + r*3 + k] = (R[r*3+0]*IC[0+k] + R[r*3+1]*IC[3+k]) + R[r*3+2]*IC[6+k];
}

// One 256-thread block (4 waves) per (bn, w) column.
//   phase 1: wave ws computes softmax+geometry for rows h=2*ws, 2*ws+1
//   phase 2: wave ws scatters depths d = ws, ws+4, ... with cross-row
//            register merge (rows hitting the same voxel share one atomic).
__global__ __launch_bounds__(256) void lss_scatter_col(const float* __restrict__ cam_out,
                                                       const float* __restrict__ trans,
                                                       const float* __restrict__ post_trans,
                                                       const float* __restrict__ prep,
                                                       float* __restrict__ dst) {
  #pragma clang fp contract(off)
  const int blk  = blockIdx.x;        // 0 .. BN*FW-1
  const int bn   = blk / FW;
  const int w    = blk % FW;
  const int b    = bn / NCAM;
  const int tid  = threadIdx.x;
  const int ws   = tid >> 6;          // wave id 0..3
  const int lane = tid & 63;

  __shared__ float sP[9], sM[9], sPT[3], sTR[3];
  __shared__ float sDep[FH][DNUM + 1];
  __shared__ int   sVox[FH][DNUM + 1];
  __shared__ float sFeat[FH][CAMC];

  if (tid < 9)       sP[tid]      = prep[bn*18 + tid];
  else if (tid < 18) sM[tid-9]    = prep[bn*18 + tid];
  else if (tid < 21) sPT[tid-18]  = post_trans[bn*3 + (tid-18)];
  else if (tid < 24) sTR[tid-21]  = trans[bn*3 + (tid-21)];

  const int colbase = bn*CAM_STRIDE + w;   // + c*HW + h*FW

  // ---- features: 256 threads load 512 values (2 each) ----
  #pragma unroll
  for (int idx = tid; idx < FH*CAMC; idx += 256) {
    int fh = idx >> 6, c = idx & 63;
    sFeat[fh][c] = cam_out[colbase + (DNUM + c)*HW + fh*FW];
  }
  __syncthreads();   // sP/sM/sPT/sTR ready (and sFeat in flight rules)

  const float fx = (float)((double)w * (351.0 / 21.0));

  // ---- per-row softmax + geometry: wave ws handles rows 2*ws, 2*ws+1 ----
  #pragma unroll
  for (int r = 0; r < 2; r++) {
    const int h = 2*ws + r;
    float logit = (lane < DNUM) ? cam_out[colbase + lane*HW + h*FW] : -INFINITY;
    float mx = logit;
    #pragma unroll
    for (int off = 32; off >= 1; off >>= 1) mx = fmaxf(mx, __shfl_xor(mx, off, 64));
    float e = expf(logit - mx);
    float s = e;
    #pragma unroll
    for (int off = 32; off >= 1; off >>= 1) s += __shfl_xor(s, off, 64);
    if (lane < DNUM) {
      float fy = (float)((double)h * (127.0 / 7.0));
      float fz = 4.0f + (float)lane;
      float p0 = fx - sPT[0], p1 = fy - sPT[1], p2 = fz - sPT[2];
      float q0 = (sP[0]*p0 + sP[1]*p1) + sP[2]*p2;
      float q1 = (sP[3]*p0 + sP[4]*p1) + sP[5]*p2;
      float q2 = (sP[6]*p0 + sP[7]*p1) + sP[8]*p2;
      float r0 = q0*q2, r1 = q1*q2, r2 = q2;
      float g0 = ((sM[0]*r0 + sM[1]*r1) + sM[2]*r2) + sTR[0];
      float g1 = ((sM[3]*r0 + sM[4]*r1) + sM[5]*r2) + sTR[1];
      float g2 = ((sM[6]*r0 + sM[7]*r1) + sM[8]*r2) + sTR[2];
      int ix = (int)((g0 + 50.0f) / 0.5f);
      int iy = (int)((g1 + 50.0f) / 0.5f);
      int iz = (int)((g2 + 10.0f) / 20.0f);
      bool kept = (ix >= 0) & (ix < NXX) & (iy >= 0) & (iy < NXY) & (iz == 0);
      sVox[h][lane] = kept ? (ix*NXY + iy) : -1;
      sDep[h][lane] = e / s;
    }
  }
  __syncthreads();

  // ---- merged scatter: wave ws takes depths d = ws, ws+4, ...; lane = c ----
  float* __restrict__ sb = dst + (size_t)b*KVOX*CAMC + lane;
  for (int d = ws; d < DNUM; d += 4) {
    unsigned done = 0;
    #pragma unroll
    for (int h = 0; h < FH; h++) {
      if ((done >> h) & 1u) continue;
      int v = sVox[h][d];            // wave-uniform (broadcast LDS read)
      if (v < 0) continue;
      float wsum = sDep[h][d] * sFeat[h][lane];
      #pragma unroll
      for (int h2 = h + 1; h2 < FH; h2++) {
        if (sVox[h2][d] == v) {
          wsum += sDep[h2][d] * sFeat[h2][lane];
          done |= 1u << h2;
        }
      }
      atomicAdd(sb + (size_t)v*CAMC, wsum);   // 64 lanes -> 4 cache lines
    }
  }
}

// (B, XY, C) -> (B, C, XY) tiled transpose; writes EVERY output element.
__global__ __launch_bounds__(256) void lss_transpose(const float* __restrict__ src,
                                                     float* __restrict__ out) {
  __shared__ float tile[64][65];
  const int b  = blockIdx.y;
  const int v0 = blockIdx.x * 64;                 // 625 * 64 = 40000 exactly
  const int tx = threadIdx.x & 63;
  const int ty = threadIdx.x >> 6;                // 0..3
  const float* s = src + ((size_t)b*KVOX + v0) * CAMC;
  #pragma unroll
  for (int r = ty; r < 64; r += 4)
    tile[r][tx] = s[r*CAMC + tx];                 // coalesced
  __syncthreads();
  float* dstp = out + (size_t)b*OUT_PER_B + v0;
  #pragma unroll
  for (int r = ty; r < 64; r += 4)
    dstp[(size_t)r*KVOX + tx] = tile[tx][r];      // coalesced, bank-conflict-free
}

// Fallback (tiny ws): direct atomic scatter into out (round-1 structure).
__global__ __launch_bounds__(64) void lss_scatter_direct(const float* __restrict__ cam_out,
                                                         const float* __restrict__ trans,
                                                         const float* __restrict__ post_trans,
                                                         const float* __restrict__ prep,
                                                         float* __restrict__ out) {
  #pragma clang fp contract(off)
  const int blk = blockIdx.x;
  const int bn  = blk / HW;
  const int pix = blk % HW;
  const int h   = pix / FW;
  const int w   = pix % FW;
  const int b   = bn / NCAM;
  const int tid = threadIdx.x;
  __shared__ float sP[9], sM[9], sPT[3], sTR[3];
  __shared__ float sDepth[DNUM];
  __shared__ int   sVoff[DNUM];
  if (tid < 9)       sP[tid]      = prep[bn*18 + tid];
  else if (tid < 18) sM[tid-9]    = prep[bn*18 + tid];
  else if (tid < 21) sPT[tid-18]  = post_trans[bn*3 + (tid-18)];
  else if (tid < 24) sTR[tid-21]  = trans[bn*3 + (tid-21)];
  __syncthreads();
  const int base = bn*CAM_STRIDE + h*FW + w;
  float logit = (tid < DNUM) ? cam_out[base + tid*HW] : -INFINITY;
  float mx = logit;
  #pragma unroll
  for (int off = 32; off >= 1; off >>= 1) mx = fmaxf(mx, __shfl_xor(mx, off, 64));
  float e = expf(logit - mx);
  float s = e;
  #pragma unroll
  for (int off = 32; off >= 1; off >>= 1) s += __shfl_xor(s, off, 64);
  float depth = e / s;
  if (tid < DNUM) {
    float fx = (float)((double)w * (351.0 / 21.0));
    float fy = (float)((double)h * (127.0 / 7.0));
    float fz = 4.0f + (float)tid;
    float p0 = fx - sPT[0], p1 = fy - sPT[1], p2 = fz - sPT[2];
    float q0 = (sP[0]*p0 + sP[1]*p1) + sP[2]*p2;
    float q1 = (sP[3]*p0 + sP[4]*p1) + sP[5]*p2;
    float q2 = (sP[6]*p0 + sP[7]*p1) + sP[8]*p2;
    float r0 = q0*q2, r1 = q1*q2, r2 = q2;
    float g0 = ((sM[0]*r0 + sM[1]*r1) + sM[2]*r2) + sTR[0];
    float g1 = ((sM[3]*r0 + sM[4]*r1) + sM[5]*r2) + sTR[1];
    float g2 = ((sM[6]*r0 + sM[7]*r1) + sM[8]*r2) + sTR[2];
    int ix = (int)((g0 + 50.0f) / 0.5f);
    int iy = (int)((g1 + 50.0f) / 0.5f);
    int iz = (int)((g2 + 10.0f) / 20.0f);
    bool kept = (ix >= 0) & (ix < NXX) & (iy >= 0) & (iy < NXY) & (iz == 0);
    sVoff[tid]  = kept ? (ix*NXY + iy) : -1;
    sDepth[tid] = depth;
  }
  __syncthreads();
  const float feat = cam_out[base + (DNUM + tid)*HW];
  float* outb = out + (size_t)b*OUT_PER_B + (size_t)tid*KVOX;
  #pragma unroll 1
  for (int d = 0; d < DNUM; d++) {
    int v = sVoff[d];
    if (v >= 0) atomicAdd(outb + v, sDepth[d] * feat);
  }
}

extern "C" void kernel_launch(void* const* d_in, const int* in_sizes, int n_in,
                              void* d_out, int out_size, void* d_ws, size_t ws_size,
                              hipStream_t stream) {
  const float* cam_out    = (const float*)d_in[0];
  const float* rots       = (const float*)d_in[1];
  const float* trans      = (const float*)d_in[2];
  const float* intrins    = (const float*)d_in[3];
  const float* post_rots  = (const float*)d_in[4];
  const float* post_trans = (const float*)d_in[5];
  float* out = (float*)d_out;
  float* ws  = (float*)d_ws;

  const size_t scratch_bytes = SCRATCH_FLOATS * sizeof(float);
  const bool use_scratch = ws_size >= scratch_bytes + (size_t)BN*18*sizeof(float);
  float* prep = use_scratch ? (ws + SCRATCH_FLOATS) : ws;

  lss_prep<<<1, 64, 0, stream>>>(rots, intrins, post_rots, prep);

  if (use_scratch) {
    hipMemsetAsync(ws, 0, scratch_bytes, stream);
    lss_scatter_col<<<BN * FW, 256, 0, stream>>>(cam_out, trans, post_trans, prep, ws);
    dim3 g(KVOX / 64, NB);
    lss_transpose<<<g, 256, 0, stream>>>(ws, out);
  } else {
    hipMemsetAsync(out, 0, (size_t)out_size * sizeof(float), stream);
    lss_scatter_direct<<<BN * HW, 64, 0, stream>>>(cam_out, trans, post_trans, prep, out);
  }
}

// Round 6
// 94.752 us; speedup vs baseline: 2.0998x; 1.0802x over previous
//
#include <hip/hip_runtime.h>
#include <math.h>

// LiftSplatShoot constants
#define DNUM 41
#define FH 8
#define FW 22
#define CAMC 64
#define NB 8
#define NCAM 6
#define BN 48
#define NXX 200
#define NXY 200
#define KVOX 40000                // NXX*NXY (NXZ=1)
#define CAM_CH (DNUM + CAMC)      // 105
#define HW (FH * FW)              // 176
#define CAM_STRIDE (CAM_CH * HW)  // 18480
#define OUT_PER_B (CAMC * KVOX)   // 2,560,000
#define SCRATCH_FLOATS ((size_t)NB * KVOX * CAMC)   // 20,480,000 floats = 81.92 MB

// Replicates reference safe_inverse_3x3 in float32, same op order, no fma.
__device__ __forceinline__ void inv3x3(const float* __restrict__ m, float* __restrict__ o) {
  #pragma clang fp contract(off)
  float a=m[0], b=m[1], c=m[2];
  float d=m[3], e=m[4], f=m[5];
  float g=m[6], h=m[7], i=m[8];
  float A  =  e*i - f*h;
  float Bc = -(d*i - f*g);
  float Cc =  d*h - e*g;
  float Dc = -(b*i - c*h);
  float E  =  a*i - c*g;
  float F  = -(a*h - b*g);
  float G  =  b*f - c*e;
  float H  = -(a*f - c*d);
  float I  =  a*e - b*d;
  float det = fmaxf((a*A + b*Bc) + c*Cc, 1e-8f);
  o[0]=A/det;  o[1]=Dc/det; o[2]=G/det;
  o[3]=Bc/det; o[4]=E/det;  o[5]=H/det;
  o[6]=Cc/det; o[7]=F/det;  o[8]=I/det;
}

// One 512-thread block (8 waves) per (bn, w) column.
//   thread 0: computes P = inv(post_rots), M = rots @ inv(intrins) (inlined prep)
//   wave ws (=row h): softmax + geometry for its row
//   scatter: wave ws handles depths d = ws, ws+8, ... with cross-row register
//            merge (rows hitting the same voxel share one atomic).
__global__ __launch_bounds__(512) void lss_scatter_col(const float* __restrict__ cam_out,
                                                       const float* __restrict__ rots,
                                                       const float* __restrict__ trans,
                                                       const float* __restrict__ intrins,
                                                       const float* __restrict__ post_rots,
                                                       const float* __restrict__ post_trans,
                                                       float* __restrict__ dst) {
  #pragma clang fp contract(off)
  const int blk  = blockIdx.x;        // 0 .. BN*FW-1
  const int bn   = blk / FW;
  const int w    = blk % FW;
  const int b    = bn / NCAM;
  const int tid  = threadIdx.x;
  const int wv   = tid >> 6;          // wave id 0..7 == row h
  const int lane = tid & 63;

  __shared__ float sP[9], sM[9], sPT[3], sTR[3];
  __shared__ float sDep[FH][DNUM + 1];
  __shared__ int   sVox[FH][DNUM + 1];
  __shared__ float sFeat[FH][CAMC];

  // ---- inlined prep (thread 0) + small vec loads (threads 8..13) ----
  if (tid == 0) {
    float P[9], IC[9], M[9];
    inv3x3(post_rots + bn*9, P);
    inv3x3(intrins + bn*9, IC);
    const float* R = rots + bn*9;
    #pragma unroll
    for (int r = 0; r < 3; r++)
      #pragma unroll
      for (int k = 0; k < 3; k++)
        M[r*3+k] = (R[r*3+0]*IC[0+k] + R[r*3+1]*IC[3+k]) + R[r*3+2]*IC[6+k];
    #pragma unroll
    for (int j = 0; j < 9; j++) { sP[j] = P[j]; sM[j] = M[j]; }
  } else if (tid >= 8 && tid < 11) {
    sPT[tid-8]  = post_trans[bn*3 + (tid-8)];
  } else if (tid >= 11 && tid < 14) {
    sTR[tid-11] = trans[bn*3 + (tid-11)];
  }

  const int colbase = bn*CAM_STRIDE + w;   // + c*HW + h*FW

  // ---- features: 512 threads, exactly one value each ----
  {
    int fh = tid >> 6, c = tid & 63;
    sFeat[fh][c] = cam_out[colbase + (DNUM + c)*HW + fh*FW];
  }
  __syncthreads();

  const float fx = (float)((double)w * (351.0 / 21.0));

  // ---- per-row softmax + geometry: wave wv handles row h = wv ----
  {
    const int h = wv;
    float logit = (lane < DNUM) ? cam_out[colbase + lane*HW + h*FW] : -INFINITY;
    float mx = logit;
    #pragma unroll
    for (int off = 32; off >= 1; off >>= 1) mx = fmaxf(mx, __shfl_xor(mx, off, 64));
    float e = expf(logit - mx);
    float s = e;
    #pragma unroll
    for (int off = 32; off >= 1; off >>= 1) s += __shfl_xor(s, off, 64);
    if (lane < DNUM) {
      float fy = (float)((double)h * (127.0 / 7.0));
      float fz = 4.0f + (float)lane;
      float p0 = fx - sPT[0], p1 = fy - sPT[1], p2 = fz - sPT[2];
      float q0 = (sP[0]*p0 + sP[1]*p1) + sP[2]*p2;
      float q1 = (sP[3]*p0 + sP[4]*p1) + sP[5]*p2;
      float q2 = (sP[6]*p0 + sP[7]*p1) + sP[8]*p2;
      float r0 = q0*q2, r1 = q1*q2, r2 = q2;
      float g0 = ((sM[0]*r0 + sM[1]*r1) + sM[2]*r2) + sTR[0];
      float g1 = ((sM[3]*r0 + sM[4]*r1) + sM[5]*r2) + sTR[1];
      float g2 = ((sM[6]*r0 + sM[7]*r1) + sM[8]*r2) + sTR[2];
      int ix = (int)((g0 + 50.0f) / 0.5f);
      int iy = (int)((g1 + 50.0f) / 0.5f);
      int iz = (int)((g2 + 10.0f) / 20.0f);
      bool kept = (ix >= 0) & (ix < NXX) & (iy >= 0) & (iy < NXY) & (iz == 0);
      sVox[h][lane] = kept ? (ix*NXY + iy) : -1;
      sDep[h][lane] = e / s;
    }
  }
  __syncthreads();

  // ---- merged scatter: wave wv takes depths d = wv, wv+8, ...; lane = c ----
  float* __restrict__ sb = dst + (size_t)b*KVOX*CAMC + lane;
  for (int d = wv; d < DNUM; d += 8) {
    unsigned done = 0;
    #pragma unroll
    for (int h = 0; h < FH; h++) {
      if ((done >> h) & 1u) continue;
      int v = sVox[h][d];            // wave-uniform (broadcast LDS read)
      if (v < 0) continue;
      float wsum = sDep[h][d] * sFeat[h][lane];
      #pragma unroll
      for (int h2 = h + 1; h2 < FH; h2++) {
        if (sVox[h2][d] == v) {
          wsum += sDep[h2][d] * sFeat[h2][lane];
          done |= 1u << h2;
        }
      }
      atomicAdd(sb + (size_t)v*CAMC, wsum);   // 64 lanes -> 4 cache lines
    }
  }
}

// (B, XY, C) -> (B, C, XY) tiled transpose; writes EVERY output element.
__global__ __launch_bounds__(256) void lss_transpose(const float* __restrict__ src,
                                                     float* __restrict__ out) {
  __shared__ float tile[64][65];
  const int b  = blockIdx.y;
  const int v0 = blockIdx.x * 64;                 // 625 * 64 = 40000 exactly
  const int tx = threadIdx.x & 63;
  const int ty = threadIdx.x >> 6;                // 0..3
  const float* s = src + ((size_t)b*KVOX + v0) * CAMC;
  #pragma unroll
  for (int r = ty; r < 64; r += 4)
    tile[r][tx] = s[r*CAMC + tx];                 // coalesced
  __syncthreads();
  float* dstp = out + (size_t)b*OUT_PER_B + v0;
  #pragma unroll
  for (int r = ty; r < 64; r += 4)
    dstp[(size_t)r*KVOX + tx] = tile[tx][r];      // coalesced, bank-conflict-free
}

// Fallback (tiny ws): per-(b,n) prep then direct atomic scatter into out.
__global__ void lss_prep(const float* __restrict__ rots,
                         const float* __restrict__ intrins,
                         const float* __restrict__ post_rots,
                         float* __restrict__ prep) {
  #pragma clang fp contract(off)
  int bn = threadIdx.x;
  if (bn >= BN) return;
  float P[9], IC[9];
  inv3x3(post_rots + bn*9, P);
  inv3x3(intrins + bn*9, IC);
  const float* R = rots + bn*9;
  float* o = prep + bn*18;
  #pragma unroll
  for (int j = 0; j < 9; j++) o[j] = P[j];
  #pragma unroll
  for (int r = 0; r < 3; r++)
    #pragma unroll
    for (int k = 0; k < 3; k++)
      o[9 + r*3 + k] = (R[r*3+0]*IC[0+k] + R[r*3+1]*IC[3+k]) + R[r*3+2]*IC[6+k];
}

__global__ __launch_bounds__(64) void lss_scatter_direct(const float* __restrict__ cam_out,
                                                         const float* __restrict__ trans,
                                                         const float* __restrict__ post_trans,
                                                         const float* __restrict__ prep,
                                                         float* __restrict__ out) {
  #pragma clang fp contract(off)
  const int blk = blockIdx.x;
  const int bn  = blk / HW;
  const int pix = blk % HW;
  const int h   = pix / FW;
  const int w   = pix % FW;
  const int b   = bn / NCAM;
  const int tid = threadIdx.x;
  __shared__ float sP[9], sM[9], sPT[3], sTR[3];
  __shared__ float sDepth[DNUM];
  __shared__ int   sVoff[DNUM];
  if (tid < 9)       sP[tid]      = prep[bn*18 + tid];
  else if (tid < 18) sM[tid-9]    = prep[bn*18 + tid];
  else if (tid < 21) sPT[tid-18]  = post_trans[bn*3 + (tid-18)];
  else if (tid < 24) sTR[tid-21]  = trans[bn*3 + (tid-21)];
  __syncthreads();
  const int base = bn*CAM_STRIDE + h*FW + w;
  float logit = (tid < DNUM) ? cam_out[base + tid*HW] : -INFINITY;
  float mx = logit;
  #pragma unroll
  for (int off = 32; off >= 1; off >>= 1) mx = fmaxf(mx, __shfl_xor(mx, off, 64));
  float e = expf(logit - mx);
  float s = e;
  #pragma unroll
  for (int off = 32; off >= 1; off >>= 1) s += __shfl_xor(s, off, 64);
  float depth = e / s;
  if (tid < DNUM) {
    float fx = (float)((double)w * (351.0 / 21.0));
    float fy = (float)((double)h * (127.0 / 7.0));
    float fz = 4.0f + (float)tid;
    float p0 = fx - sPT[0], p1 = fy - sPT[1], p2 = fz - sPT[2];
    float q0 = (sP[0]*p0 + sP[1]*p1) + sP[2]*p2;
    float q1 = (sP[3]*p0 + sP[4]*p1) + sP[5]*p2;
    float q2 = (sP[6]*p0 + sP[7]*p1) + sP[8]*p2;
    float r0 = q0*q2, r1 = q1*q2, r2 = q2;
    float g0 = ((sM[0]*r0 + sM[1]*r1) + sM[2]*r2) + sTR[0];
    float g1 = ((sM[3]*r0 + sM[4]*r1) + sM[5]*r2) + sTR[1];
    float g2 = ((sM[6]*r0 + sM[7]*r1) + sM[8]*r2) + sTR[2];
    int ix = (int)((g0 + 50.0f) / 0.5f);
    int iy = (int)((g1 + 50.0f) / 0.5f);
    int iz = (int)((g2 + 10.0f) / 20.0f);
    bool kept = (ix >= 0) & (ix < NXX) & (iy >= 0) & (iy < NXY) & (iz == 0);
    sVoff[tid]  = kept ? (ix*NXY + iy) : -1;
    sDepth[tid] = depth;
  }
  __syncthreads();
  const float feat = cam_out[base + (DNUM + tid)*HW];
  float* outb = out + (size_t)b*OUT_PER_B + (size_t)tid*KVOX;
  #pragma unroll 1
  for (int d = 0; d < DNUM; d++) {
    int v = sVoff[d];
    if (v >= 0) atomicAdd(outb + v, sDepth[d] * feat);
  }
}

extern "C" void kernel_launch(void* const* d_in, const int* in_sizes, int n_in,
                              void* d_out, int out_size, void* d_ws, size_t ws_size,
                              hipStream_t stream) {
  const float* cam_out    = (const float*)d_in[0];
  const float* rots       = (const float*)d_in[1];
  const float* trans      = (const float*)d_in[2];
  const float* intrins    = (const float*)d_in[3];
  const float* post_rots  = (const float*)d_in[4];
  const float* post_trans = (const float*)d_in[5];
  float* out = (float*)d_out;
  float* ws  = (float*)d_ws;

  const size_t scratch_bytes = SCRATCH_FLOATS * sizeof(float);
  const bool use_scratch = ws_size >= scratch_bytes;

  if (use_scratch) {
    hipMemsetAsync(ws, 0, scratch_bytes, stream);
    lss_scatter_col<<<BN * FW, 512, 0, stream>>>(cam_out, rots, trans, intrins,
                                                 post_rots, post_trans, ws);
    dim3 g(KVOX / 64, NB);
    lss_transpose<<<g, 256, 0, stream>>>(ws, out);
  } else {
    float* prep = ws;   // BN*18 floats
    hipMemsetAsync(out, 0, (size_t)out_size * sizeof(float), stream);
    lss_prep<<<1, 64, 0, stream>>>(rots, intrins, post_rots, prep);
    lss_scatter_direct<<<BN * HW, 64, 0, stream>>>(cam_out, trans, post_trans, prep, out);
  }
}